// Round 2
// baseline (80.787 us; speedup 1.0000x reference)
//
#include <hip/hip_runtime.h>
#include <math.h>

// CircleLoss (m=1, GAMMA=1):
//   a_i = -|op - pc_i| * (pc_i - delta_p),  b_i = |nc_i - on| * (nc_i - delta_n)
//   loss = log(1 + (sum_i exp(a_i)) * (sum_i exp(b_i)))
// True exponents reach ~+9000 -> exp overflows (ref output is inf). We compute
// the numerically-stable value via online log-sum-exp:
//   loss = softplus(Mp + log Sp + Mn + log Sn)
// Memory-bound streaming reduce: 402 MB read once -> ~64 us roofline.

#define NEG_BIG (-1.0e30f)

__device__ __forceinline__ float margin_val(const void* p) {
    // Python scalar 1 -> int32 array most likely; decode robustly.
    int iv = *(const int*)p;
    if (iv > -(1 << 23) && iv < (1 << 23)) return (float)iv;
    return *(const float*)p;
}

// Combine two (max, scaled-sum) logsumexp states.
__device__ __forceinline__ void lse_combine(float& m, float& s, float om, float os) {
    float M = fmaxf(m, om);
    // With NEG_BIG sentinels, expf(NEG_BIG - M) underflows to 0 (no NaN).
    s = s * expf(m - M) + os * expf(om - M);
    m = M;
}

// Accumulate one new exponent `a` (weight 1) into (m, s).
__device__ __forceinline__ void lse_add(float& m, float& s, float a) {
    if (a > m) {
        s = s * expf(m - a) + 1.0f;
        m = a;
    } else {
        s += expf(a - m);
    }
}

__global__ __launch_bounds__(256) void circle_partial(
    const float* __restrict__ anchor,
    const float* __restrict__ positive,
    const float* __restrict__ negative,
    const void* __restrict__ margin_p,
    float4* __restrict__ ws,   // per-block (mp, sp, mn, sn)
    int N)
{
    const float m       = margin_val(margin_p);
    const float delta_p = 1.0f - m;
    const float delta_n = m;
    const float op      = 1.0f + m;
    const float on      = -m;

    const int lane          = threadIdx.x & 63;
    const int wid           = threadIdx.x >> 6;
    const int waves_per_blk = blockDim.x >> 6;
    const int gwave         = blockIdx.x * waves_per_blk + wid;
    const int nwaves        = gridDim.x * waves_per_blk;

    float mp = NEG_BIG, sp = 0.0f;
    float mn = NEG_BIG, sn = 0.0f;

    // One wave per row: 64 lanes x 2 float4 = 512 floats, fully coalesced.
    for (int row = gwave; row < N; row += nwaves) {
        const float4* a4 = (const float4*)(anchor   + (size_t)row * 512);
        const float4* p4 = (const float4*)(positive + (size_t)row * 512);
        const float4* n4 = (const float4*)(negative + (size_t)row * 512);
        float4 a0 = a4[lane], a1 = a4[lane + 64];
        float4 p0 = p4[lane], p1 = p4[lane + 64];
        float4 n0 = n4[lane], n1 = n4[lane + 64];

        float pos = a0.x*p0.x + a0.y*p0.y + a0.z*p0.z + a0.w*p0.w
                  + a1.x*p1.x + a1.y*p1.y + a1.z*p1.z + a1.w*p1.w;
        float neg = a0.x*n0.x + a0.y*n0.y + a0.z*n0.z + a0.w*n0.w
                  + a1.x*n1.x + a1.y*n1.y + a1.z*n1.z + a1.w*n1.w;

        #pragma unroll
        for (int off = 32; off > 0; off >>= 1) {
            pos += __shfl_xor(pos, off, 64);
            neg += __shfl_xor(neg, off, 64);
        }

        // All lanes hold identical row dots; keep identical LSE state per lane.
        float ap = -fabsf(op - pos) * (pos - delta_p);
        float an =  fabsf(neg - on) * (neg - delta_n);
        lse_add(mp, sp, ap);
        lse_add(mn, sn, an);
    }

    __shared__ float s_mp[8], s_sp[8], s_mn[8], s_sn[8];
    if (lane == 0) { s_mp[wid] = mp; s_sp[wid] = sp; s_mn[wid] = mn; s_sn[wid] = sn; }
    __syncthreads();
    if (threadIdx.x == 0) {
        float Mp = NEG_BIG, Sp = 0.0f, Mn = NEG_BIG, Sn = 0.0f;
        for (int i = 0; i < waves_per_blk; ++i) {
            lse_combine(Mp, Sp, s_mp[i], s_sp[i]);
            lse_combine(Mn, Sn, s_mn[i], s_sn[i]);
        }
        ws[blockIdx.x] = make_float4(Mp, Sp, Mn, Sn);  // plain overwrite, no ws init needed
    }
}

__global__ __launch_bounds__(256) void circle_final(
    const float4* __restrict__ ws,
    int nblk,
    float* __restrict__ out)
{
    float mp = NEG_BIG, sp = 0.0f;
    float mn = NEG_BIG, sn = 0.0f;
    for (int i = threadIdx.x; i < nblk; i += blockDim.x) {
        float4 v = ws[i];
        lse_combine(mp, sp, v.x, v.y);
        lse_combine(mn, sn, v.z, v.w);
    }
    #pragma unroll
    for (int off = 32; off > 0; off >>= 1) {
        float omp = __shfl_xor(mp, off, 64);
        float osp = __shfl_xor(sp, off, 64);
        float omn = __shfl_xor(mn, off, 64);
        float osn = __shfl_xor(sn, off, 64);
        lse_combine(mp, sp, omp, osp);
        lse_combine(mn, sn, omn, osn);
    }
    __shared__ float s_mp[4], s_sp[4], s_mn[4], s_sn[4];
    const int lane = threadIdx.x & 63;
    const int wid  = threadIdx.x >> 6;
    if (lane == 0) { s_mp[wid] = mp; s_sp[wid] = sp; s_mn[wid] = mn; s_sn[wid] = sn; }
    __syncthreads();
    if (threadIdx.x == 0) {
        float Mp = NEG_BIG, Sp = 0.0f, Mn = NEG_BIG, Sn = 0.0f;
        for (int i = 0; i < 4; ++i) {
            lse_combine(Mp, Sp, s_mp[i], s_sp[i]);
            lse_combine(Mn, Sn, s_mn[i], s_sn[i]);
        }
        // L = log(Sp*Sn) + Mp + Mn ; loss = log(1 + e^L) computed stably.
        float L = Mp + Mn + logf(Sp) + logf(Sn);
        float loss = fmaxf(L, 0.0f) + log1pf(expf(-fabsf(L)));
        out[0] = loss;
    }
}

extern "C" void kernel_launch(void* const* d_in, const int* in_sizes, int n_in,
                              void* d_out, int out_size, void* d_ws, size_t ws_size,
                              hipStream_t stream) {
    const float* anchor   = (const float*)d_in[0];
    const float* positive = (const float*)d_in[1];
    const float* negative = (const float*)d_in[2];
    const void*  margin   = d_in[3];

    const int N = in_sizes[0] >> 9;  // D = 512 per reference

    int nblk = 2048;  // 8 blocks/CU; 8 rows per wave
    const size_t need = (size_t)nblk * sizeof(float4);
    if (ws_size < need) nblk = (int)(ws_size / sizeof(float4));

    circle_partial<<<nblk, 256, 0, stream>>>(anchor, positive, negative, margin,
                                             (float4*)d_ws, N);
    circle_final<<<1, 256, 0, stream>>>((const float4*)d_ws, nblk, (float*)d_out);
}